// Round 6
// baseline (95.010 us; speedup 1.0000x reference)
//
#include <hip/hip_runtime.h>
#include <math.h>

// Problem dims (fixed)
#define NN      16
#define WIDTH   64
#define TT      2048
#define NBINS   2048
#define NROWS   32768      // NN*TT
#define NELEM   2097152    // NN*WIDTH*TT
#define NBLK_VQ 1024       // vq_main grid (2 blocks per 64-row group)
#define NBLK_EP 512        // epilogue grid

typedef unsigned short u16;
typedef unsigned int   u32;
typedef __attribute__((ext_vector_type(8))) short short8;   // 8 bf16 (4 VGPRs)
typedef __attribute__((ext_vector_type(4))) float f32x4;

#define MFMA_BF16 __builtin_amdgcn_mfma_f32_16x16x32_bf16
#define KEYMASK   0xFFFFF800u
// DBIAS must exceed max|2*dot(x,cb)| so the discriminant is ALWAYS > 0
// (u32 float-ordering breaks for negatives). |dot| sigma ~0.031 -> 0.25 = 8σ
// per candidate; 0.5 gives 16σ. Round-4/5 used 0.125 -> wrong bins (bug).
#define DBIAS     0.5f

__device__ __forceinline__ u16 f2bf(float f) {            // RNE f32 -> bf16 bits
    u32 u = __float_as_uint(f);
    u32 r = u + 0x7FFFu + ((u >> 16) & 1u);
    return (u16)(r >> 16);
}

// ---------------------------------------------------------------------------
// Prep: cbT = bf16(cb) in MFMA-tiled layout; cbnC = ||cb||^2 + DBIAS.
// Also inits gkeys to 0xFF.. and zeroes the epilogue done counter.
// cbT chunk layout: [bin16][kc][kseg][col][8elem]; k = kc*32 + kseg*8 + i.
// ---------------------------------------------------------------------------
__global__ __launch_bounds__(256) void cbprep_k(const float* __restrict__ cb,
                                                u16* __restrict__ cbT,
                                                float* __restrict__ cbnC,
                                                u32* __restrict__ gkeys,
                                                u32* __restrict__ done_ctr) {
    int g = blockIdx.x * 256 + threadIdx.x;    // grid 32 -> 8192 threads
    if (g == 0) *done_ctr = 0;
    // init global keys (4 per thread)
    *(uint4*)&gkeys[g * 4] = make_uint4(0xFFFFFFFFu, 0xFFFFFFFFu,
                                        0xFFFFFFFFu, 0xFFFFFFFFu);
    int b = g >> 2, q = g & 3;                 // bin, quarter (16 k each)
    const float4* p = (const float4*)(cb + (size_t)b * 64) + q * 4;
    const int base = (b >> 4) * 1024 + (b & 15) * 8;
    float s = 0.f;
#pragma unroll
    for (int c = 0; c < 2; ++c) {              // octet o = q*2 + c
        float4 v0 = p[c * 2], v1 = p[c * 2 + 1];
        s += v0.x * v0.x + v0.y * v0.y + v0.z * v0.z + v0.w * v0.w;
        s += v1.x * v1.x + v1.y * v1.y + v1.z * v1.z + v1.w * v1.w;
        short8 h = { (short)f2bf(v0.x), (short)f2bf(v0.y), (short)f2bf(v0.z),
                     (short)f2bf(v0.w), (short)f2bf(v1.x), (short)f2bf(v1.y),
                     (short)f2bf(v1.z), (short)f2bf(v1.w) };
        int o = q * 2 + c;
        *(short8*)&cbT[base + (o >> 2) * 512 + (o & 3) * 128] = h;
    }
    s += __shfl_xor(s, 1, 64);
    s += __shfl_xor(s, 2, 64);
    if (q == 0) cbnC[b] = s + DBIAS;
}

// ---------------------------------------------------------------------------
// Main: block = 64 rows x 1024 bins (8 tiles of 128). 4 waves; wave bg owns
// 32 bins of each tile, all 64 rows. B streamed from L2 via 2-deep NAMED
// register double-buffer (no barriers in loop, no runtime indexing).
// Argmin via sortable u32 keys: d = cbnC[b] - 2*dot > 0 by construction,
// key = (bits(d) & ~0x7FF) | bin. Per-row merge: LDS atomicMin, then one
// global atomicMin per row (commutative -> deterministic).
// ---------------------------------------------------------------------------
__global__ __launch_bounds__(256, 4) void vq_main_k(
    const float* __restrict__ x, const u16* __restrict__ cbT,
    const float* __restrict__ cbnC, u32* __restrict__ gkeys) {
    // A: [t][k] bf16, 64x64, XOR-swizzled: elem = t*64 + (k ^ ((t&7)<<3))
    __shared__ __align__(16) u16 Ah[64 * 64];
    __shared__ u32 kq_row[64];

    const int tid  = threadIdx.x;
    const int lane = tid & 63;
    const int bg   = tid >> 6;      // wave 0..3 = bin sub-slice
    const int col  = lane & 15;
    const int kseg = lane >> 4;     // 0..3

    const int rgid = blockIdx.x >> 1;      // 64-row group 0..511
    const int half = blockIdx.x & 1;       // bin half (tiles 0..7 / 8..15)
    const int r0 = rgid * 64;              // rows r0..r0+63; row = n*2048 + t
    const int n  = r0 >> 11;
    const int t0 = r0 & 2047;

    if (tid < 64) kq_row[tid] = 0xFFFFFFFFu;

    const int fragoff = kseg * 128 + col * 8;   // within a 1KB cbT chunk

    // --- 2 named B-register sets (NO runtime indexing anywhere) ---
    short8 bA00, bA01, bA10, bA11, bB00, bB01, bB10, bB11;
    float  cnA0, cnA1, cnB0, cnB1;

#define PF(S00, S01, S10, S11, C0, C1, T) do {                                \
        const int _gt = half * 8 + (T);                                       \
        const int _bb = _gt * 128 + bg * 32 + col;                            \
        const int _c16 = (_gt * 8 + bg * 2) * 1024 + fragoff;                 \
        C0 = cbnC[_bb];  C1 = cbnC[_bb + 16];                                 \
        S00 = *(const short8*)&cbT[_c16];                                     \
        S01 = *(const short8*)&cbT[_c16 + 512];                               \
        S10 = *(const short8*)&cbT[_c16 + 1024];                              \
        S11 = *(const short8*)&cbT[_c16 + 1536];                              \
    } while (0)

    PF(bA00, bA01, bA10, bA11, cnA0, cnA1, 0);
    PF(bB00, bB01, bB10, bB11, cnB0, cnB1, 1);

    // ---- Stage A: x fp32 -> bf16 [t][k] swizzled (latency hides B PFs) ----
    {
        const int t  = tid & 63;
        const int kb = tid >> 6;     // 0..3
        const float* xp = x + (size_t)n * (WIDTH * TT) + t0 + t;
        const int sw = (t & 7) << 3;
#pragma unroll
        for (int it = 0; it < 8; ++it) {
            int k2 = kb * 16 + it * 2;
            float v0 = xp[(size_t)k2 * TT];
            float v1 = xp[(size_t)(k2 + 1) * TT];
            u32 pack = (u32)f2bf(v0) | ((u32)f2bf(v1) << 16);
            *(u32*)&Ah[t * 64 + (k2 ^ sw)] = pack;   // k2 even -> pair intact
        }
    }
    __syncthreads();

    // ---- A fragments in registers (held across all 8 tiles) ----
    short8 afh[4][2];
#pragma unroll
    for (int rs = 0; rs < 4; ++rs) {
        const int rt = rs * 16 + col;
        const int sw = (rt & 7) << 3;
#pragma unroll
        for (int kc = 0; kc < 2; ++kc)
            afh[rs][kc] = *(const short8*)&Ah[rt * 64 + ((kc * 32 + kseg * 8) ^ sw)];
    }

    u32 keys[16];
#pragma unroll
    for (int i = 0; i < 16; ++i) keys[i] = 0xFFFFFFFFu;

#define CM(S00, S01, S10, S11, C0, C1, T) do {                                \
        const u32 bin0 = (u32)((half * 8 + (T)) * 128 + bg * 32 + col);       \
        _Pragma("unroll")                                                     \
        for (int rs = 0; rs < 4; ++rs) {                                      \
            f32x4 a0 = {0.f, 0.f, 0.f, 0.f}, a1 = {0.f, 0.f, 0.f, 0.f};       \
            a0 = MFMA_BF16(afh[rs][0], S00, a0, 0, 0, 0);                     \
            a0 = MFMA_BF16(afh[rs][1], S01, a0, 0, 0, 0);                     \
            a1 = MFMA_BF16(afh[rs][0], S10, a1, 0, 0, 0);                     \
            a1 = MFMA_BF16(afh[rs][1], S11, a1, 0, 0, 0);                     \
            _Pragma("unroll")                                                 \
            for (int jj = 0; jj < 4; ++jj) {                                  \
                float d0 = fmaf(-2.f, a0[jj], C0);                            \
                float d1 = fmaf(-2.f, a1[jj], C1);                            \
                u32 k0 = (__float_as_uint(d0) & KEYMASK) | bin0;              \
                u32 k1 = (__float_as_uint(d1) & KEYMASK) | (bin0 + 16u);      \
                int li = rs * 4 + jj;                                         \
                u32 km = k0 < k1 ? k0 : k1;          /* min3-fusable */       \
                keys[li] = km < keys[li] ? km : keys[li];                     \
            }                                                                 \
        }                                                                     \
    } while (0)

    CM(bA00, bA01, bA10, bA11, cnA0, cnA1, 0);
    PF(bA00, bA01, bA10, bA11, cnA0, cnA1, 2);
    CM(bB00, bB01, bB10, bB11, cnB0, cnB1, 1);
    PF(bB00, bB01, bB10, bB11, cnB0, cnB1, 3);
    CM(bA00, bA01, bA10, bA11, cnA0, cnA1, 2);
    PF(bA00, bA01, bA10, bA11, cnA0, cnA1, 4);
    CM(bB00, bB01, bB10, bB11, cnB0, cnB1, 3);
    PF(bB00, bB01, bB10, bB11, cnB0, cnB1, 5);
    CM(bA00, bA01, bA10, bA11, cnA0, cnA1, 4);
    PF(bA00, bA01, bA10, bA11, cnA0, cnA1, 6);
    CM(bB00, bB01, bB10, bB11, cnB0, cnB1, 5);
    PF(bB00, bB01, bB10, bB11, cnB0, cnB1, 7);
    CM(bA00, bA01, bA10, bA11, cnA0, cnA1, 6);
    CM(bB00, bB01, bB10, bB11, cnB0, cnB1, 7);
#undef CM
#undef PF

    // ---- reduce across 16 col-lanes (u32 min = value then lowest bin) ----
#pragma unroll
    for (int m = 1; m <= 8; m <<= 1) {
#pragma unroll
        for (int i = 0; i < 16; ++i) {
            u32 ok = (u32)__shfl_xor((int)keys[i], m, 64);
            keys[i] = ok < keys[i] ? ok : keys[i];
        }
    }
    // ---- cross-wave merge via LDS atomicMin ----
    if (col == 0) {
#pragma unroll
        for (int rs = 0; rs < 4; ++rs)
#pragma unroll
            for (int jj = 0; jj < 4; ++jj)
                atomicMin(&kq_row[rs * 16 + kseg * 4 + jj], keys[rs * 4 + jj]);
    }
    __syncthreads();
    // ---- global per-row merge (commutative u32 min -> deterministic) ----
    if (tid < 64) atomicMin(&gkeys[r0 + tid], kq_row[tid]);
}

// ---------------------------------------------------------------------------
// Epilogue: raw-view gather (out[o] = cb[key[o>>6] & 0x7FF][o&63]), STE
// arithmetic out = x + (q - x), loss & fit partials (xnorm recomputed from
// the x we must read anyway). Last-finishing block writes the two scalars.
// ---------------------------------------------------------------------------
__global__ __launch_bounds__(256) void epi_k(
    const float* __restrict__ x, const float* __restrict__ cb,
    const u32* __restrict__ gkeys, float* __restrict__ out,
    float* __restrict__ loss_part, float* __restrict__ fit_part,
    u32* __restrict__ done_ctr) {
    __shared__ float red_l[4], red_f[4];
    __shared__ float ss[4], ff[4];
    __shared__ int   isLast;

    const int tid  = threadIdx.x;
    const int lane = tid & 63;
    const int wv   = tid >> 6;
    const int q    = tid & 3;             // quarter of a 64-float row
    const int row  = blockIdx.x * 64 + (tid >> 2);
    const size_t ob = (size_t)row * 64 + q * 16;

    const u32 key = gkeys[row];
    const int id  = (int)(key & 0x7FFu);
    const float d = __uint_as_float(key & KEYMASK) - DBIAS;

    const float* qp = cb + (size_t)id * 64 + q * 16;
    float4 q0 = *(const float4*)(qp);
    float4 q1 = *(const float4*)(qp + 4);
    float4 q2 = *(const float4*)(qp + 8);
    float4 q3 = *(const float4*)(qp + 12);
    float4 xv0 = *(const float4*)(x + ob);
    float4 xv1 = *(const float4*)(x + ob + 4);
    float4 xv2 = *(const float4*)(x + ob + 8);
    float4 xv3 = *(const float4*)(x + ob + 12);

    float ls = 0.f, xn = 0.f;
#define STE(QV, XV, OFF) do {                                                 \
        float4 qo;                                                            \
        qo.x = XV.x + (QV.x - XV.x); qo.y = XV.y + (QV.y - XV.y);             \
        qo.z = XV.z + (QV.z - XV.z); qo.w = XV.w + (QV.w - XV.w);             \
        *(float4*)(out + ob + OFF) = qo;                                      \
        float dx = QV.x - XV.x, dy = QV.y - XV.y;                             \
        float dz = QV.z - XV.z, dw = QV.w - XV.w;                             \
        ls += dx * dx + dy * dy + dz * dz + dw * dw;                          \
        xn += XV.x * XV.x + XV.y * XV.y + XV.z * XV.z + XV.w * XV.w;          \
    } while (0)
    STE(q0, xv0, 0); STE(q1, xv1, 4); STE(q2, xv2, 8); STE(q3, xv3, 12);
#undef STE
    // per-row xnorm via quad reduce; lane q==0 contributes the row's fit
    xn += __shfl_xor(xn, 1, 64);
    xn += __shfl_xor(xn, 2, 64);
    float fv = (q == 0) ? sqrtf(fmaxf(xn + d, 0.f)) : 0.f;
#pragma unroll
    for (int m = 32; m >= 1; m >>= 1) {
        ls += __shfl_xor(ls, m, 64);
        fv += __shfl_xor(fv, m, 64);
    }
    if (lane == 0) { red_l[wv] = ls; red_f[wv] = fv; }
    __syncthreads();
    if (tid == 0) {
        loss_part[blockIdx.x] = red_l[0] + red_l[1] + red_l[2] + red_l[3];
        fit_part[blockIdx.x]  = red_f[0] + red_f[1] + red_f[2] + red_f[3];
    }

    // ---- last-block final reduction (deterministic fixed-order sums) ----
    __threadfence();
    if (tid == 0) {
        u32 old = atomicAdd(done_ctr, 1u);
        isLast = (old == NBLK_EP - 1) ? 1 : 0;
    }
    __syncthreads();
    if (isLast) {
        __threadfence();
        float s = 0.f, f = 0.f;
        for (int i = tid; i < NBLK_EP; i += 256) {
            s += loss_part[i]; f += fit_part[i];
        }
#pragma unroll
        for (int m = 32; m >= 1; m >>= 1) {
            s += __shfl_xor(s, m, 64);
            f += __shfl_xor(f, m, 64);
        }
        if (lane == 0) { ss[wv] = s; ff[wv] = f; }
        __syncthreads();
        if (tid == 0) {
            float loss_sum = ss[0] + ss[1] + ss[2] + ss[3];
            float fit_sum  = ff[0] + ff[1] + ff[2] + ff[3];
            // loss = codebook_loss + 0.25*commit_loss = 1.25 * mean((q-x)^2)
            out[NELEM]     = 1.25f * loss_sum / (float)NELEM;
            out[NELEM + 1] = fit_sum / (float)NROWS;
        }
    }
}

// ---------------------------------------------------------------------------
extern "C" void kernel_launch(void* const* d_in, const int* in_sizes, int n_in,
                              void* d_out, int out_size, void* d_ws, size_t ws_size,
                              hipStream_t stream) {
    const float* x  = (const float*)d_in[0];   // (16,64,2048) fp32
    const float* cb = (const float*)d_in[1];   // (2048,64) fp32
    float* out = (float*)d_out;                // [2097152 quantized][loss][fit]

    char* ws = (char*)d_ws;
    float* cbnC      = (float*)(ws);            // 8 KB
    u16*   cbT       = (u16*)  (ws + 8192);     // 256 KB
    u32*   gkeys     = (u32*)  (ws + 270336);   // 128 KB
    float* loss_part = (float*)(ws + 401408);   // 2 KB
    float* fit_part  = (float*)(ws + 403456);   // 2 KB
    u32*   done_ctr  = (u32*)  (ws + 405504);   // 4 B

    cbprep_k<<<32,      256, 0, stream>>>(cb, cbT, cbnC, gkeys, done_ctr);
    vq_main_k<<<NBLK_VQ, 256, 0, stream>>>(x, cbT, cbnC, gkeys);
    epi_k<<<NBLK_EP,    256, 0, stream>>>(x, cb, gkeys, out, loss_part,
                                          fit_part, done_ctr);
}

// Round 7
// 28.516 us; speedup vs baseline: 3.3318x; 3.3318x over previous
//
#include <hip/hip_runtime.h>
#include <math.h>

// Problem dims (fixed)
#define NN      16
#define WIDTH   64
#define TT      2048
#define NBINS   2048
#define NROWS   32768      // NN*TT
#define NELEM   2097152    // NN*WIDTH*TT
#define NBLK_VQ 1024       // vq_main grid (2 blocks per 64-row group)
#define NBLK_EP 512        // epilogue grid

typedef unsigned short u16;
typedef unsigned int   u32;
typedef __attribute__((ext_vector_type(8))) short short8;   // 8 bf16 (4 VGPRs)
typedef __attribute__((ext_vector_type(4))) float f32x4;

#define MFMA_BF16 __builtin_amdgcn_mfma_f32_16x16x32_bf16
#define KEYMASK   0xFFFFF800u
// DBIAS must exceed max|2*dot(x,cb)| so the discriminant is ALWAYS > 0
// (u32 float-ordering breaks for negatives). |dot| sigma ~0.031 -> 0.5 = 16σ.
#define DBIAS     0.5f

__device__ __forceinline__ u16 f2bf(float f) {            // RNE f32 -> bf16 bits
    u32 u = __float_as_uint(f);
    u32 r = u + 0x7FFFu + ((u >> 16) & 1u);
    return (u16)(r >> 16);
}

// ---------------------------------------------------------------------------
// Prep: cbT = bf16(cb) in MFMA-tiled layout; cbnC = ||cb||^2 + DBIAS.
// Also inits gkeys to 0xFF...
// cbT chunk layout: [bin16][kc][kseg][col][8elem]; k = kc*32 + kseg*8 + i.
// ---------------------------------------------------------------------------
__global__ __launch_bounds__(256) void cbprep_k(const float* __restrict__ cb,
                                                u16* __restrict__ cbT,
                                                float* __restrict__ cbnC,
                                                u32* __restrict__ gkeys) {
    int g = blockIdx.x * 256 + threadIdx.x;    // grid 32 -> 8192 threads
    // init global keys (4 per thread)
    *(uint4*)&gkeys[g * 4] = make_uint4(0xFFFFFFFFu, 0xFFFFFFFFu,
                                        0xFFFFFFFFu, 0xFFFFFFFFu);
    int b = g >> 2, q = g & 3;                 // bin, quarter (16 k each)
    const float4* p = (const float4*)(cb + (size_t)b * 64) + q * 4;
    const int base = (b >> 4) * 1024 + (b & 15) * 8;
    float s = 0.f;
#pragma unroll
    for (int c = 0; c < 2; ++c) {              // octet o = q*2 + c
        float4 v0 = p[c * 2], v1 = p[c * 2 + 1];
        s += v0.x * v0.x + v0.y * v0.y + v0.z * v0.z + v0.w * v0.w;
        s += v1.x * v1.x + v1.y * v1.y + v1.z * v1.z + v1.w * v1.w;
        short8 h = { (short)f2bf(v0.x), (short)f2bf(v0.y), (short)f2bf(v0.z),
                     (short)f2bf(v0.w), (short)f2bf(v1.x), (short)f2bf(v1.y),
                     (short)f2bf(v1.z), (short)f2bf(v1.w) };
        int o = q * 2 + c;
        *(short8*)&cbT[base + (o >> 2) * 512 + (o & 3) * 128] = h;
    }
    s += __shfl_xor(s, 1, 64);
    s += __shfl_xor(s, 2, 64);
    if (q == 0) cbnC[b] = s + DBIAS;
}

// ---------------------------------------------------------------------------
// Main: block = 64 rows x 1024 bins (8 tiles of 128). 4 waves; wave bg owns
// 32 bins of each tile, all 64 rows. B streamed from L2 via 2-deep NAMED
// register double-buffer (no barriers in loop, no runtime indexing).
// Argmin via sortable u32 keys: d = cbnC[b] - 2*dot > 0 by construction,
// key = (bits(d) & ~0x7FF) | bin. Per-row merge: LDS atomicMin, then one
// global atomicMin per row (commutative -> deterministic).
// NO __threadfence anywhere (device fences forced serialized L2 writebacks
// in rounds 5/6 - the 88us stall).
// ---------------------------------------------------------------------------
__global__ __launch_bounds__(256, 4) void vq_main_k(
    const float* __restrict__ x, const u16* __restrict__ cbT,
    const float* __restrict__ cbnC, u32* __restrict__ gkeys) {
    // A: [t][k] bf16, 64x64, XOR-swizzled: elem = t*64 + (k ^ ((t&7)<<3))
    __shared__ __align__(16) u16 Ah[64 * 64];
    __shared__ u32 kq_row[64];

    const int tid  = threadIdx.x;
    const int lane = tid & 63;
    const int bg   = tid >> 6;      // wave 0..3 = bin sub-slice
    const int col  = lane & 15;
    const int kseg = lane >> 4;     // 0..3

    const int rgid = blockIdx.x >> 1;      // 64-row group 0..511
    const int half = blockIdx.x & 1;       // bin half (tiles 0..7 / 8..15)
    const int r0 = rgid * 64;              // rows r0..r0+63; row = n*2048 + t
    const int n  = r0 >> 11;
    const int t0 = r0 & 2047;

    if (tid < 64) kq_row[tid] = 0xFFFFFFFFu;

    const int fragoff = kseg * 128 + col * 8;   // within a 1KB cbT chunk

    // --- 2 named B-register sets (NO runtime indexing anywhere) ---
    short8 bA00, bA01, bA10, bA11, bB00, bB01, bB10, bB11;
    float  cnA0, cnA1, cnB0, cnB1;

#define PF(S00, S01, S10, S11, C0, C1, T) do {                                \
        const int _gt = half * 8 + (T);                                       \
        const int _bb = _gt * 128 + bg * 32 + col;                            \
        const int _c16 = (_gt * 8 + bg * 2) * 1024 + fragoff;                 \
        C0 = cbnC[_bb];  C1 = cbnC[_bb + 16];                                 \
        S00 = *(const short8*)&cbT[_c16];                                     \
        S01 = *(const short8*)&cbT[_c16 + 512];                               \
        S10 = *(const short8*)&cbT[_c16 + 1024];                              \
        S11 = *(const short8*)&cbT[_c16 + 1536];                              \
    } while (0)

    PF(bA00, bA01, bA10, bA11, cnA0, cnA1, 0);
    PF(bB00, bB01, bB10, bB11, cnB0, cnB1, 1);

    // ---- Stage A: x fp32 -> bf16 [t][k] swizzled (latency hides B PFs) ----
    {
        const int t  = tid & 63;
        const int kb = tid >> 6;     // 0..3
        const float* xp = x + (size_t)n * (WIDTH * TT) + t0 + t;
        const int sw = (t & 7) << 3;
#pragma unroll
        for (int it = 0; it < 8; ++it) {
            int k2 = kb * 16 + it * 2;
            float v0 = xp[(size_t)k2 * TT];
            float v1 = xp[(size_t)(k2 + 1) * TT];
            u32 pack = (u32)f2bf(v0) | ((u32)f2bf(v1) << 16);
            *(u32*)&Ah[t * 64 + (k2 ^ sw)] = pack;   // k2 even -> pair intact
        }
    }
    __syncthreads();

    // ---- A fragments in registers (held across all 8 tiles) ----
    short8 afh[4][2];
#pragma unroll
    for (int rs = 0; rs < 4; ++rs) {
        const int rt = rs * 16 + col;
        const int sw = (rt & 7) << 3;
#pragma unroll
        for (int kc = 0; kc < 2; ++kc)
            afh[rs][kc] = *(const short8*)&Ah[rt * 64 + ((kc * 32 + kseg * 8) ^ sw)];
    }

    u32 keys[16];
#pragma unroll
    for (int i = 0; i < 16; ++i) keys[i] = 0xFFFFFFFFu;

#define CM(S00, S01, S10, S11, C0, C1, T) do {                                \
        const u32 bin0 = (u32)((half * 8 + (T)) * 128 + bg * 32 + col);       \
        _Pragma("unroll")                                                     \
        for (int rs = 0; rs < 4; ++rs) {                                      \
            f32x4 a0 = {0.f, 0.f, 0.f, 0.f}, a1 = {0.f, 0.f, 0.f, 0.f};       \
            a0 = MFMA_BF16(afh[rs][0], S00, a0, 0, 0, 0);                     \
            a0 = MFMA_BF16(afh[rs][1], S01, a0, 0, 0, 0);                     \
            a1 = MFMA_BF16(afh[rs][0], S10, a1, 0, 0, 0);                     \
            a1 = MFMA_BF16(afh[rs][1], S11, a1, 0, 0, 0);                     \
            _Pragma("unroll")                                                 \
            for (int jj = 0; jj < 4; ++jj) {                                  \
                float d0 = fmaf(-2.f, a0[jj], C0);                            \
                float d1 = fmaf(-2.f, a1[jj], C1);                            \
                u32 k0 = (__float_as_uint(d0) & KEYMASK) | bin0;              \
                u32 k1 = (__float_as_uint(d1) & KEYMASK) | (bin0 + 16u);      \
                int li = rs * 4 + jj;                                         \
                u32 km = k0 < k1 ? k0 : k1;          /* min3-fusable */       \
                keys[li] = km < keys[li] ? km : keys[li];                     \
            }                                                                 \
        }                                                                     \
    } while (0)

    CM(bA00, bA01, bA10, bA11, cnA0, cnA1, 0);
    PF(bA00, bA01, bA10, bA11, cnA0, cnA1, 2);
    CM(bB00, bB01, bB10, bB11, cnB0, cnB1, 1);
    PF(bB00, bB01, bB10, bB11, cnB0, cnB1, 3);
    CM(bA00, bA01, bA10, bA11, cnA0, cnA1, 2);
    PF(bA00, bA01, bA10, bA11, cnA0, cnA1, 4);
    CM(bB00, bB01, bB10, bB11, cnB0, cnB1, 3);
    PF(bB00, bB01, bB10, bB11, cnB0, cnB1, 5);
    CM(bA00, bA01, bA10, bA11, cnA0, cnA1, 4);
    PF(bA00, bA01, bA10, bA11, cnA0, cnA1, 6);
    CM(bB00, bB01, bB10, bB11, cnB0, cnB1, 5);
    PF(bB00, bB01, bB10, bB11, cnB0, cnB1, 7);
    CM(bA00, bA01, bA10, bA11, cnA0, cnA1, 6);
    CM(bB00, bB01, bB10, bB11, cnB0, cnB1, 7);
#undef CM
#undef PF

    // ---- reduce across 16 col-lanes (u32 min = value then lowest bin) ----
#pragma unroll
    for (int m = 1; m <= 8; m <<= 1) {
#pragma unroll
        for (int i = 0; i < 16; ++i) {
            u32 ok = (u32)__shfl_xor((int)keys[i], m, 64);
            keys[i] = ok < keys[i] ? ok : keys[i];
        }
    }
    // ---- cross-wave merge via LDS atomicMin ----
    if (col == 0) {
#pragma unroll
        for (int rs = 0; rs < 4; ++rs)
#pragma unroll
            for (int jj = 0; jj < 4; ++jj)
                atomicMin(&kq_row[rs * 16 + kseg * 4 + jj], keys[rs * 4 + jj]);
    }
    __syncthreads();
    // ---- global per-row merge (commutative u32 min -> deterministic) ----
    if (tid < 64) atomicMin(&gkeys[r0 + tid], kq_row[tid]);
}

// ---------------------------------------------------------------------------
// Epilogue: raw-view gather (out[o] = cb[key[o>>6] & 0x7FF][o&63]), STE
// arithmetic out = x + (q - x), loss & fit partials (xnorm recomputed from
// the x we must read anyway). NO fences, NO global atomics.
// ---------------------------------------------------------------------------
__global__ __launch_bounds__(256) void epi_k(
    const float* __restrict__ x, const float* __restrict__ cb,
    const u32* __restrict__ gkeys, float* __restrict__ out,
    float* __restrict__ loss_part, float* __restrict__ fit_part) {
    __shared__ float red_l[4], red_f[4];

    const int tid  = threadIdx.x;
    const int lane = tid & 63;
    const int wv   = tid >> 6;
    const int q    = tid & 3;             // quarter of a 64-float row
    const int row  = blockIdx.x * 64 + (tid >> 2);
    const size_t ob = (size_t)row * 64 + q * 16;

    const u32 key = gkeys[row];
    const int id  = (int)(key & 0x7FFu);
    const float d = __uint_as_float(key & KEYMASK) - DBIAS;

    const float* qp = cb + (size_t)id * 64 + q * 16;
    float4 q0 = *(const float4*)(qp);
    float4 q1 = *(const float4*)(qp + 4);
    float4 q2 = *(const float4*)(qp + 8);
    float4 q3 = *(const float4*)(qp + 12);
    float4 xv0 = *(const float4*)(x + ob);
    float4 xv1 = *(const float4*)(x + ob + 4);
    float4 xv2 = *(const float4*)(x + ob + 8);
    float4 xv3 = *(const float4*)(x + ob + 12);

    float ls = 0.f, xn = 0.f;
#define STE(QV, XV, OFF) do {                                                 \
        float4 qo;                                                            \
        qo.x = XV.x + (QV.x - XV.x); qo.y = XV.y + (QV.y - XV.y);             \
        qo.z = XV.z + (QV.z - XV.z); qo.w = XV.w + (QV.w - XV.w);             \
        *(float4*)(out + ob + OFF) = qo;                                      \
        float dx = QV.x - XV.x, dy = QV.y - XV.y;                             \
        float dz = QV.z - XV.z, dw = QV.w - XV.w;                             \
        ls += dx * dx + dy * dy + dz * dz + dw * dw;                          \
        xn += XV.x * XV.x + XV.y * XV.y + XV.z * XV.z + XV.w * XV.w;          \
    } while (0)
    STE(q0, xv0, 0); STE(q1, xv1, 4); STE(q2, xv2, 8); STE(q3, xv3, 12);
#undef STE
    // per-row xnorm via quad reduce; lane q==0 contributes the row's fit
    xn += __shfl_xor(xn, 1, 64);
    xn += __shfl_xor(xn, 2, 64);
    float fv = (q == 0) ? sqrtf(fmaxf(xn + d, 0.f)) : 0.f;
#pragma unroll
    for (int m = 32; m >= 1; m >>= 1) {
        ls += __shfl_xor(ls, m, 64);
        fv += __shfl_xor(fv, m, 64);
    }
    if (lane == 0) { red_l[wv] = ls; red_f[wv] = fv; }
    __syncthreads();
    if (tid == 0) {
        loss_part[blockIdx.x] = red_l[0] + red_l[1] + red_l[2] + red_l[3];
        fit_part[blockIdx.x]  = red_f[0] + red_f[1] + red_f[2] + red_f[3];
    }
}

// ---------------------------------------------------------------------------
// Final deterministic reduction -> loss, fit scalars (1 block)
// ---------------------------------------------------------------------------
__global__ __launch_bounds__(256) void final_k(
    const float* __restrict__ loss_part, const float* __restrict__ fit_part,
    float* __restrict__ out) {
    int tid = threadIdx.x;
    float s = loss_part[tid] + loss_part[tid + 256];
    float f = fit_part[tid] + fit_part[tid + 256];
#pragma unroll
    for (int m = 32; m >= 1; m >>= 1) {
        s += __shfl_xor(s, m, 64);
        f += __shfl_xor(f, m, 64);
    }
    __shared__ float ss[4], ff[4];
    if ((tid & 63) == 0) { ss[tid >> 6] = s; ff[tid >> 6] = f; }
    __syncthreads();
    if (tid == 0) {
        float loss_sum = ss[0] + ss[1] + ss[2] + ss[3];
        float fit_sum  = ff[0] + ff[1] + ff[2] + ff[3];
        // loss = codebook_loss + 0.25*commit_loss = 1.25 * mean((q-x)^2)
        out[NELEM]     = 1.25f * loss_sum / (float)NELEM;
        out[NELEM + 1] = fit_sum / (float)NROWS;
    }
}

// ---------------------------------------------------------------------------
extern "C" void kernel_launch(void* const* d_in, const int* in_sizes, int n_in,
                              void* d_out, int out_size, void* d_ws, size_t ws_size,
                              hipStream_t stream) {
    const float* x  = (const float*)d_in[0];   // (16,64,2048) fp32
    const float* cb = (const float*)d_in[1];   // (2048,64) fp32
    float* out = (float*)d_out;                // [2097152 quantized][loss][fit]

    char* ws = (char*)d_ws;
    float* cbnC      = (float*)(ws);            // 8 KB
    u16*   cbT       = (u16*)  (ws + 8192);     // 256 KB
    u32*   gkeys     = (u32*)  (ws + 270336);   // 128 KB
    float* loss_part = (float*)(ws + 401408);   // 2 KB
    float* fit_part  = (float*)(ws + 403456);   // 2 KB

    cbprep_k<<<32,      256, 0, stream>>>(cb, cbT, cbnC, gkeys);
    vq_main_k<<<NBLK_VQ, 256, 0, stream>>>(x, cbT, cbnC, gkeys);
    epi_k<<<NBLK_EP,    256, 0, stream>>>(x, cb, gkeys, out, loss_part, fit_part);
    final_k<<<1,        256, 0, stream>>>(loss_part, fit_part, out);
}

// Round 8
// 28.214 us; speedup vs baseline: 3.3675x; 1.0107x over previous
//
#include <hip/hip_runtime.h>
#include <math.h>

// Problem dims (fixed)
#define NN      16
#define WIDTH   64
#define TT      2048
#define NBINS   2048
#define NROWS   32768      // NN*TT
#define NELEM   2097152    // NN*WIDTH*TT
#define NBLK_VQ 1024       // 32 rows per block, all 2048 bins

typedef unsigned short u16;
typedef unsigned int   u32;
typedef __attribute__((ext_vector_type(8))) short short8;   // 8 bf16 (4 VGPRs)
typedef __attribute__((ext_vector_type(4))) float f32x4;

#define MFMA_BF16 __builtin_amdgcn_mfma_f32_16x16x32_bf16
#define KEYMASK   0xFFFFF800u
// DBIAS must exceed max|2*dot(x,cb)| so the discriminant is ALWAYS > 0
// (u32 float-ordering breaks for negatives). |dot| sigma ~0.031 -> 0.5 = 16σ.
#define DBIAS     0.5f

__device__ __forceinline__ u16 f2bf(float f) {            // RNE f32 -> bf16 bits
    u32 u = __float_as_uint(f);
    u32 r = u + 0x7FFFu + ((u >> 16) & 1u);
    return (u16)(r >> 16);
}

// ---------------------------------------------------------------------------
// Prep: cbT = bf16(cb) in MFMA-tiled layout; cbnC = ||cb||^2 + DBIAS.
// cbT chunk layout: [bin16][kc][kseg][col][8elem]; k = kc*32 + kseg*8 + i.
// ---------------------------------------------------------------------------
__global__ __launch_bounds__(256) void cbprep_k(const float* __restrict__ cb,
                                                u16* __restrict__ cbT,
                                                float* __restrict__ cbnC) {
    int g = blockIdx.x * 256 + threadIdx.x;    // grid 32 -> 8192 threads
    int b = g >> 2, q = g & 3;                 // bin, quarter (16 k each)
    const float4* p = (const float4*)(cb + (size_t)b * 64) + q * 4;
    const int base = (b >> 4) * 1024 + (b & 15) * 8;
    float s = 0.f;
#pragma unroll
    for (int c = 0; c < 2; ++c) {              // octet o = q*2 + c
        float4 v0 = p[c * 2], v1 = p[c * 2 + 1];
        s += v0.x * v0.x + v0.y * v0.y + v0.z * v0.z + v0.w * v0.w;
        s += v1.x * v1.x + v1.y * v1.y + v1.z * v1.z + v1.w * v1.w;
        short8 h = { (short)f2bf(v0.x), (short)f2bf(v0.y), (short)f2bf(v0.z),
                     (short)f2bf(v0.w), (short)f2bf(v1.x), (short)f2bf(v1.y),
                     (short)f2bf(v1.z), (short)f2bf(v1.w) };
        int o = q * 2 + c;
        *(short8*)&cbT[base + (o >> 2) * 512 + (o & 3) * 128] = h;
    }
    s += __shfl_xor(s, 1, 64);
    s += __shfl_xor(s, 2, 64);
    if (q == 0) cbnC[b] = s + DBIAS;
}

// ---------------------------------------------------------------------------
// Main: block = 32 rows x ALL 2048 bins (16 tiles of 128). 4 waves; wave bg
// owns 32 bins of each tile, all 32 rows (2 MFMA row-tiles). B streamed from
// L2 via 2-deep NAMED register double-buffer (no barriers in the loop, no
// runtime indexing). Argmin via sortable u32 keys: d = cbnC[b] - 2*dot > 0,
// key = (bits(d) & ~0x7FF) | bin. Merge: shuffle + LDS atomicMin (block-local
// only -- block owns its rows). FUSED epilogue: raw-view gather + STE write
// + exact fp32 loss/fit partials (x re-read is L2/L1-hot: just staged it).
// NO global atomics, NO fences.
// ---------------------------------------------------------------------------
__global__ __launch_bounds__(256, 4) void vq_main_k(
    const float* __restrict__ x, const u16* __restrict__ cbT,
    const float* __restrict__ cbnC, const float* __restrict__ cb,
    float* __restrict__ out, float* __restrict__ loss_part,
    float* __restrict__ fit_part) {
    // A: [t][k] bf16, 32x64, XOR-swizzled: elem = t*64 + (k ^ ((t&7)<<3))
    __shared__ __align__(16) u16 Ah[32 * 64];
    __shared__ u32 kq_row[32];
    __shared__ float red_l[4], red_f[4];

    const int tid  = threadIdx.x;
    const int lane = tid & 63;
    const int bg   = tid >> 6;      // wave 0..3 = bin sub-slice
    const int col  = lane & 15;
    const int kseg = lane >> 4;     // 0..3

    const int r0 = blockIdx.x * 32;        // rows r0..r0+31; row = n*2048 + t
    const int n  = r0 >> 11;
    const int t0 = r0 & 2047;

    if (tid < 32) kq_row[tid] = 0xFFFFFFFFu;

    const int fragoff = kseg * 128 + col * 8;   // within a 1KB cbT chunk

    // --- 2 named B-register sets (NO runtime indexing anywhere) ---
    short8 bA00, bA01, bA10, bA11, bB00, bB01, bB10, bB11;
    float  cnA0, cnA1, cnB0, cnB1;

#define PF(S00, S01, S10, S11, C0, C1, T) do {                                \
        const int _bb = (T) * 128 + bg * 32 + col;                            \
        const int _c16 = ((T) * 8 + bg * 2) * 1024 + fragoff;                 \
        C0 = cbnC[_bb];  C1 = cbnC[_bb + 16];                                 \
        S00 = *(const short8*)&cbT[_c16];                                     \
        S01 = *(const short8*)&cbT[_c16 + 512];                               \
        S10 = *(const short8*)&cbT[_c16 + 1024];                              \
        S11 = *(const short8*)&cbT[_c16 + 1536];                              \
    } while (0)

    PF(bA00, bA01, bA10, bA11, cnA0, cnA1, 0);
    PF(bB00, bB01, bB10, bB11, cnB0, cnB1, 1);

    // ---- Stage A: x fp32 -> bf16 [t][k] swizzled (latency hides B PFs) ----
    {
        const int t  = tid & 31;
        const int kb = tid >> 5;     // 0..7
        const float* xp = x + (size_t)n * (WIDTH * TT) + t0 + t;
        const int sw = (t & 7) << 3;
#pragma unroll
        for (int it = 0; it < 4; ++it) {
            int k2 = kb * 8 + it * 2;
            float v0 = xp[(size_t)k2 * TT];
            float v1 = xp[(size_t)(k2 + 1) * TT];
            u32 pack = (u32)f2bf(v0) | ((u32)f2bf(v1) << 16);
            *(u32*)&Ah[t * 64 + (k2 ^ sw)] = pack;   // k2 even -> pair intact
        }
    }
    __syncthreads();

    // ---- A fragments in registers (held across all 16 tiles) ----
    short8 afh[2][2];
#pragma unroll
    for (int rs = 0; rs < 2; ++rs) {
        const int rt = rs * 16 + col;
        const int sw = (rt & 7) << 3;
#pragma unroll
        for (int kc = 0; kc < 2; ++kc)
            afh[rs][kc] = *(const short8*)&Ah[rt * 64 + ((kc * 32 + kseg * 8) ^ sw)];
    }

    u32 keys[8];
#pragma unroll
    for (int i = 0; i < 8; ++i) keys[i] = 0xFFFFFFFFu;

#define CM(S00, S01, S10, S11, C0, C1, T) do {                                \
        const u32 bin0 = (u32)((T) * 128 + bg * 32 + col);                    \
        _Pragma("unroll")                                                     \
        for (int rs = 0; rs < 2; ++rs) {                                      \
            f32x4 a0 = {0.f, 0.f, 0.f, 0.f}, a1 = {0.f, 0.f, 0.f, 0.f};       \
            a0 = MFMA_BF16(afh[rs][0], S00, a0, 0, 0, 0);                     \
            a0 = MFMA_BF16(afh[rs][1], S01, a0, 0, 0, 0);                     \
            a1 = MFMA_BF16(afh[rs][0], S10, a1, 0, 0, 0);                     \
            a1 = MFMA_BF16(afh[rs][1], S11, a1, 0, 0, 0);                     \
            _Pragma("unroll")                                                 \
            for (int jj = 0; jj < 4; ++jj) {                                  \
                float d0 = fmaf(-2.f, a0[jj], C0);                            \
                float d1 = fmaf(-2.f, a1[jj], C1);                            \
                u32 k0 = (__float_as_uint(d0) & KEYMASK) | bin0;              \
                u32 k1 = (__float_as_uint(d1) & KEYMASK) | (bin0 + 16u);      \
                int li = rs * 4 + jj;                                         \
                u32 km = k0 < k1 ? k0 : k1;                                   \
                keys[li] = km < keys[li] ? km : keys[li];                     \
            }                                                                 \
        }                                                                     \
    } while (0)

    CM(bA00, bA01, bA10, bA11, cnA0, cnA1, 0);
    PF(bA00, bA01, bA10, bA11, cnA0, cnA1, 2);
    CM(bB00, bB01, bB10, bB11, cnB0, cnB1, 1);
    PF(bB00, bB01, bB10, bB11, cnB0, cnB1, 3);
    CM(bA00, bA01, bA10, bA11, cnA0, cnA1, 2);
    PF(bA00, bA01, bA10, bA11, cnA0, cnA1, 4);
    CM(bB00, bB01, bB10, bB11, cnB0, cnB1, 3);
    PF(bB00, bB01, bB10, bB11, cnB0, cnB1, 5);
    CM(bA00, bA01, bA10, bA11, cnA0, cnA1, 4);
    PF(bA00, bA01, bA10, bA11, cnA0, cnA1, 6);
    CM(bB00, bB01, bB10, bB11, cnB0, cnB1, 5);
    PF(bB00, bB01, bB10, bB11, cnB0, cnB1, 7);
    CM(bA00, bA01, bA10, bA11, cnA0, cnA1, 6);
    PF(bA00, bA01, bA10, bA11, cnA0, cnA1, 8);
    CM(bB00, bB01, bB10, bB11, cnB0, cnB1, 7);
    PF(bB00, bB01, bB10, bB11, cnB0, cnB1, 9);
    CM(bA00, bA01, bA10, bA11, cnA0, cnA1, 8);
    PF(bA00, bA01, bA10, bA11, cnA0, cnA1, 10);
    CM(bB00, bB01, bB10, bB11, cnB0, cnB1, 9);
    PF(bB00, bB01, bB10, bB11, cnB0, cnB1, 11);
    CM(bA00, bA01, bA10, bA11, cnA0, cnA1, 10);
    PF(bA00, bA01, bA10, bA11, cnA0, cnA1, 12);
    CM(bB00, bB01, bB10, bB11, cnB0, cnB1, 11);
    PF(bB00, bB01, bB10, bB11, cnB0, cnB1, 13);
    CM(bA00, bA01, bA10, bA11, cnA0, cnA1, 12);
    PF(bA00, bA01, bA10, bA11, cnA0, cnA1, 14);
    CM(bB00, bB01, bB10, bB11, cnB0, cnB1, 13);
    PF(bB00, bB01, bB10, bB11, cnB0, cnB1, 15);
    CM(bA00, bA01, bA10, bA11, cnA0, cnA1, 14);
    CM(bB00, bB01, bB10, bB11, cnB0, cnB1, 15);
#undef CM
#undef PF

    // ---- reduce across 16 col-lanes (u32 min = value then lowest bin) ----
#pragma unroll
    for (int m = 1; m <= 8; m <<= 1) {
#pragma unroll
        for (int i = 0; i < 8; ++i) {
            u32 ok = (u32)__shfl_xor((int)keys[i], m, 64);
            keys[i] = ok < keys[i] ? ok : keys[i];
        }
    }
    // ---- cross-wave merge via LDS atomicMin (block owns its 32 rows) ----
    if (col == 0) {
#pragma unroll
        for (int rs = 0; rs < 2; ++rs)
#pragma unroll
            for (int jj = 0; jj < 4; ++jj)
                atomicMin(&kq_row[rs * 16 + kseg * 4 + jj], keys[rs * 4 + jj]);
    }
    __syncthreads();

    // ---- fused epilogue: raw-view gather + STE write + loss/fit partials --
    // thread -> (row = tid>>3, oct oc = tid&7): 8 floats at out[row*64+oc*8].
    // x slice was just read for staging -> L2/L1 hot.
    const int row = tid >> 3;
    const int oc  = tid & 7;
    const size_t ob = (size_t)(r0 + row) * 64 + oc * 8;
    const int id = (int)(kq_row[row] & 0x7FFu);
    const float* qp = cb + (size_t)id * 64 + oc * 8;
    float4 q0 = *(const float4*)(qp);
    float4 q1 = *(const float4*)(qp + 4);
    float4 xv0 = *(const float4*)(x + ob);
    float4 xv1 = *(const float4*)(x + ob + 4);
    float ls = 0.f;
#define STE(QV, XV, OFF) do {                                                 \
        float4 qo;                                                            \
        qo.x = XV.x + (QV.x - XV.x); qo.y = XV.y + (QV.y - XV.y);             \
        qo.z = XV.z + (QV.z - XV.z); qo.w = XV.w + (QV.w - XV.w);             \
        *(float4*)(out + ob + OFF) = qo;                                      \
        float dx = QV.x - XV.x, dy = QV.y - XV.y;                             \
        float dz = QV.z - XV.z, dw = QV.w - XV.w;                             \
        ls += dx * dx + dy * dy + dz * dz + dw * dw;                          \
    } while (0)
    STE(q0, xv0, 0); STE(q1, xv1, 4);
#undef STE
    // per-row sum across the 8 oct-lanes -> fit contribution (exact fp32)
    float ls8 = ls;
    ls8 += __shfl_xor(ls8, 1, 64);
    ls8 += __shfl_xor(ls8, 2, 64);
    ls8 += __shfl_xor(ls8, 4, 64);
    float fv = (oc == 0) ? sqrtf(ls8) : 0.f;
#pragma unroll
    for (int m = 32; m >= 1; m >>= 1) {
        ls += __shfl_xor(ls, m, 64);
        fv += __shfl_xor(fv, m, 64);
    }
    if (lane == 0) { red_l[bg] = ls; red_f[bg] = fv; }
    __syncthreads();
    if (tid == 0) {
        loss_part[blockIdx.x] = red_l[0] + red_l[1] + red_l[2] + red_l[3];
        fit_part[blockIdx.x]  = red_f[0] + red_f[1] + red_f[2] + red_f[3];
    }
}

// ---------------------------------------------------------------------------
// Final deterministic reduction -> loss, fit scalars (1 block, 1024 partials)
// ---------------------------------------------------------------------------
__global__ __launch_bounds__(256) void final_k(
    const float* __restrict__ loss_part, const float* __restrict__ fit_part,
    float* __restrict__ out) {
    int tid = threadIdx.x;
    float s = 0.f, f = 0.f;
#pragma unroll
    for (int j = 0; j < 4; ++j) {
        s += loss_part[tid + 256 * j];
        f += fit_part[tid + 256 * j];
    }
#pragma unroll
    for (int m = 32; m >= 1; m >>= 1) {
        s += __shfl_xor(s, m, 64);
        f += __shfl_xor(f, m, 64);
    }
    __shared__ float ss[4], ff[4];
    if ((tid & 63) == 0) { ss[tid >> 6] = s; ff[tid >> 6] = f; }
    __syncthreads();
    if (tid == 0) {
        float loss_sum = ss[0] + ss[1] + ss[2] + ss[3];
        float fit_sum  = ff[0] + ff[1] + ff[2] + ff[3];
        // loss = codebook_loss + 0.25*commit_loss = 1.25 * mean((q-x)^2)
        out[NELEM]     = 1.25f * loss_sum / (float)NELEM;
        out[NELEM + 1] = fit_sum / (float)NROWS;
    }
}

// ---------------------------------------------------------------------------
extern "C" void kernel_launch(void* const* d_in, const int* in_sizes, int n_in,
                              void* d_out, int out_size, void* d_ws, size_t ws_size,
                              hipStream_t stream) {
    const float* x  = (const float*)d_in[0];   // (16,64,2048) fp32
    const float* cb = (const float*)d_in[1];   // (2048,64) fp32
    float* out = (float*)d_out;                // [2097152 quantized][loss][fit]

    char* ws = (char*)d_ws;
    float* cbnC      = (float*)(ws);            // 8 KB
    u16*   cbT       = (u16*)  (ws + 8192);     // 256 KB
    float* loss_part = (float*)(ws + 270336);   // 4 KB (1024 f)
    float* fit_part  = (float*)(ws + 274432);   // 4 KB (1024 f)

    cbprep_k<<<32,       256, 0, stream>>>(cb, cbT, cbnC);
    vq_main_k<<<NBLK_VQ, 256, 0, stream>>>(x, cbT, cbnC, cb, out,
                                           loss_part, fit_part);
    final_k<<<1,         256, 0, stream>>>(loss_part, fit_part, out);
}